// Round 1
// baseline (2176.166 us; speedup 1.0000x reference)
//
#include <hip/hip_runtime.h>
#include <cstdint>
#include <cstddef>

// GCNII: h0 = relu(x@W_in + b_in); 8x { agg = Ahat @ h; s = .9 agg + .1 h0; h = relu(s @ Wl) };
// out = h@W_out + b_out.  All fp32.  Ahat = D^-1/2 (A + I) D^-1/2, deg from target column.

#define HID 128

// ---------------- preprocessing ----------------

__global__ void k_hist(const int* __restrict__ col, int E, int* __restrict__ cnt) {
  int e = blockIdx.x * blockDim.x + threadIdx.x;
  if (e < E) atomicAdd(&cnt[col[e]], 1);
}

__global__ void k_dinv(const int* __restrict__ cnt, float* __restrict__ dinv, int N) {
  int i = blockIdx.x * blockDim.x + threadIdx.x;
  if (i < N) dinv[i] = rsqrtf((float)cnt[i] + 1.0f);  // +1 self loop
}

// single-block exclusive scan of cnt[0..N) -> row_ptr[0..N]
__global__ __launch_bounds__(1024) void k_scan(const int* __restrict__ cnt,
                                               int* __restrict__ row_ptr, int N) {
  __shared__ int buf[1024];
  __shared__ int carry;
  int t = threadIdx.x;
  if (t == 0) carry = 0;
  __syncthreads();
  for (int base = 0; base < N; base += 1024) {
    int i = base + t;
    int v = (i < N) ? cnt[i] : 0;
    buf[t] = v;
    __syncthreads();
    for (int off = 1; off < 1024; off <<= 1) {
      int add = (t >= off) ? buf[t - off] : 0;
      __syncthreads();
      buf[t] += add;
      __syncthreads();
    }
    int incl = buf[t];
    int c = carry;
    if (i < N) row_ptr[i] = c + incl - v;
    __syncthreads();
    if (t == 0) carry = c + buf[1023];
    __syncthreads();
  }
  if (t == 0) row_ptr[N] = carry;
}

__global__ void k_fill(const int* __restrict__ row, const int* __restrict__ col, int E,
                       const float* __restrict__ dinv, const int* __restrict__ row_ptr,
                       int* __restrict__ fill, int* __restrict__ csr_src,
                       float* __restrict__ csr_nrm) {
  int e = blockIdx.x * blockDim.x + threadIdx.x;
  if (e >= E) return;
  int r = row[e], c = col[e];
  int p = row_ptr[c] + atomicAdd(&fill[c], 1);
  csr_src[p] = r;
  csr_nrm[p] = dinv[r] * dinv[c];
}

// ---------------- aggregation (one wave per node, atomic-free) ----------------

__global__ __launch_bounds__(256) void k_aggregate(
    const float* __restrict__ h, const float* __restrict__ x0,
    const float* __restrict__ dinv, const int* __restrict__ row_ptr,
    const int* __restrict__ csr_src, const float* __restrict__ csr_nrm,
    float* __restrict__ support, int N) {
  int node = blockIdx.x * 4 + (threadIdx.x >> 6);
  if (node >= N) return;
  int lane = threadIdx.x & 63;
  int beg = row_ptr[node], end = row_ptr[node + 1];
  float di = dinv[node];
  // self-loop term
  float2 v0 = ((const float2*)(h + (size_t)node * HID))[lane];
  float ax = di * di * v0.x;
  float ay = di * di * v0.y;
  for (int j = beg; j < end; ++j) {
    int s = csr_src[j];
    float w = csr_nrm[j];
    float2 v = ((const float2*)(h + (size_t)s * HID))[lane];
    ax = fmaf(w, v.x, ax);
    ay = fmaf(w, v.y, ay);
  }
  float2 xv = ((const float2*)(x0 + (size_t)node * HID))[lane];
  float2 o;
  o.x = 0.9f * ax + 0.1f * xv.x;
  o.y = 0.9f * ay + 0.1f * xv.y;
  ((float2*)(support + (size_t)node * HID))[lane] = o;
}

// ---------------- fp32 tiled GEMM: C[M][NC] = op(A[M][128] @ B[128][NC]) ----------------

template <int NC, bool RELU, bool BIAS>
__global__ __launch_bounds__(256) void k_gemm(const float* __restrict__ A,
                                              const float* __restrict__ B,
                                              const float* __restrict__ bias,
                                              float* __restrict__ C, int M) {
  constexpr int TN = NC / 16;             // 8 (NC=128) or 4 (NC=64)
  __shared__ float As[8][68];             // transposed tile, 16B-aligned rows
  __shared__ float Bs[8][NC];
  int tid = threadIdx.x;
  int tx = tid & 15, ty = tid >> 4;
  int row0 = blockIdx.x * 64;

  float acc[4][TN];
#pragma unroll
  for (int m = 0; m < 4; ++m)
#pragma unroll
    for (int n = 0; n < TN; ++n) acc[m][n] = 0.0f;

  int la_row = tid >> 2;        // 0..63
  int la_k = (tid & 3) * 2;     // 0,2,4,6

  for (int kk = 0; kk < 128; kk += 8) {
    int ar = row0 + la_row;
    float2 av = make_float2(0.0f, 0.0f);
    if (ar < M) av = *(const float2*)(A + (size_t)ar * 128 + kk + la_k);
    As[la_k][la_row] = av.x;
    As[la_k + 1][la_row] = av.y;
    if (NC == 128) {
      int bk = tid >> 5, bc = (tid & 31) * 4;
      *(float4*)&Bs[bk][bc] = *(const float4*)(B + (size_t)(kk + bk) * NC + bc);
    } else {
      if (tid < NC * 2) {
        int bk = tid >> 4, bc = (tid & 15) * 4;
        *(float4*)&Bs[bk][bc] = *(const float4*)(B + (size_t)(kk + bk) * NC + bc);
      }
    }
    __syncthreads();
#pragma unroll
    for (int k = 0; k < 8; ++k) {
      float a[4], b[TN];
      *(float4*)a = *(const float4*)&As[k][ty * 4];
#pragma unroll
      for (int n = 0; n < TN; n += 4)
        *(float4*)&b[n] = *(const float4*)&Bs[k][tx * TN + n];
#pragma unroll
      for (int m = 0; m < 4; ++m)
#pragma unroll
        for (int n = 0; n < TN; ++n) acc[m][n] = fmaf(a[m], b[n], acc[m][n]);
    }
    __syncthreads();
  }

#pragma unroll
  for (int m = 0; m < 4; ++m) {
    int r = row0 + ty * 4 + m;
    if (r < M) {
#pragma unroll
      for (int n = 0; n < TN; n += 4) {
        float4 o;
        o.x = acc[m][n + 0];
        o.y = acc[m][n + 1];
        o.z = acc[m][n + 2];
        o.w = acc[m][n + 3];
        if (BIAS) {
          o.x += bias[tx * TN + n + 0];
          o.y += bias[tx * TN + n + 1];
          o.z += bias[tx * TN + n + 2];
          o.w += bias[tx * TN + n + 3];
        }
        if (RELU) {
          o.x = fmaxf(o.x, 0.0f);
          o.y = fmaxf(o.y, 0.0f);
          o.z = fmaxf(o.z, 0.0f);
          o.w = fmaxf(o.w, 0.0f);
        }
        *(float4*)(C + (size_t)r * NC + tx * TN + n) = o;
      }
    }
  }
}

// ---------------- launch ----------------

extern "C" void kernel_launch(void* const* d_in, const int* in_sizes, int n_in,
                              void* d_out, int out_size, void* d_ws, size_t ws_size,
                              hipStream_t stream) {
  const float* x     = (const float*)d_in[0];
  const int*   ei    = (const int*)d_in[1];
  const float* W_in  = (const float*)d_in[2];
  const float* b_in  = (const float*)d_in[3];
  const float* Wc    = (const float*)d_in[4];
  const float* W_out = (const float*)d_in[5];
  const float* b_out = (const float*)d_in[6];
  float* out = (float*)d_out;

  const int N = in_sizes[0] / HID;   // 100000
  const int E = in_sizes[1] / 2;     // 1600000
  const int L = in_sizes[4] / (HID * HID);  // 8
  const int* row = ei;       // sources
  const int* col = ei + E;   // targets

  char* p = (char*)d_ws;
  auto alloc = [&](size_t bytes) {
    char* q = p;
    p += (bytes + 255) & ~(size_t)255;
    return q;
  };
  int*   cnt     = (int*)alloc((size_t)N * 4);
  int*   row_ptr = (int*)alloc((size_t)(N + 1) * 4);
  int*   fill    = (int*)alloc((size_t)N * 4);
  float* dinv    = (float*)alloc((size_t)N * 4);
  int*   csr_src = (int*)alloc((size_t)E * 4);
  float* csr_nrm = (float*)alloc((size_t)E * 4);
  float* x0      = (float*)alloc((size_t)N * HID * 4);
  float* hbuf    = (float*)alloc((size_t)N * HID * 4);
  float* sup     = (float*)alloc((size_t)N * HID * 4);
  (void)ws_size; (void)n_in; (void)out_size;

  hipMemsetAsync(cnt, 0, (size_t)N * 4, stream);
  hipMemsetAsync(fill, 0, (size_t)N * 4, stream);

  k_hist<<<(E + 255) / 256, 256, 0, stream>>>(col, E, cnt);
  k_dinv<<<(N + 255) / 256, 256, 0, stream>>>(cnt, dinv, N);
  k_scan<<<1, 1024, 0, stream>>>(cnt, row_ptr, N);
  k_fill<<<(E + 255) / 256, 256, 0, stream>>>(row, col, E, dinv, row_ptr, fill,
                                              csr_src, csr_nrm);

  int ggrid = (N + 63) / 64;
  // input projection -> x0
  k_gemm<128, true, true><<<ggrid, 256, 0, stream>>>(x, W_in, b_in, x0, N);

  const float* hin = x0;
  for (int l = 0; l < L; ++l) {
    k_aggregate<<<(N + 3) / 4, 256, 0, stream>>>(hin, x0, dinv, row_ptr, csr_src,
                                                 csr_nrm, sup, N);
    k_gemm<128, true, false><<<ggrid, 256, 0, stream>>>(
        sup, Wc + (size_t)l * HID * HID, nullptr, hbuf, N);
    hin = hbuf;
  }
  // output projection
  k_gemm<64, false, true><<<ggrid, 256, 0, stream>>>(hbuf, W_out, b_out, out, N);
}

// Round 2
// 1313.051 us; speedup vs baseline: 1.6573x; 1.6573x over previous
//
#include <hip/hip_runtime.h>
#include <hip/hip_fp16.h>
#include <cstdint>
#include <cstddef>

// GCNII: h0 = relu(x@W_in + b_in); 8x { agg = Ahat @ h; s = .9 agg + .1 h0; h = relu(s @ Wl) };
// out = h@W_out + b_out.  Ahat = D^-1/2 (A + I) D^-1/2 (deg over targets, +1 self loop).
// h stored fp16 for the gather (halves dominant traffic); GEMM accumulate + support fp32.

#define HID 128

// ---------------- preprocessing ----------------

__global__ void k_hist(const int* __restrict__ col, int E, int* __restrict__ cnt) {
  int e = blockIdx.x * blockDim.x + threadIdx.x;
  if (e < E) atomicAdd(&cnt[col[e]], 1);
}

__global__ void k_dinv(const int* __restrict__ cnt, float* __restrict__ dinv, int N) {
  int i = blockIdx.x * blockDim.x + threadIdx.x;
  if (i < N) dinv[i] = rsqrtf((float)cnt[i] + 1.0f);  // +1 self loop
}

// hierarchical exclusive scan: blocksum -> scan partials (1 block) -> per-block scan+offset
__global__ __launch_bounds__(256) void k_blocksum(const int* __restrict__ cnt,
                                                  int* __restrict__ bsum, int N) {
  __shared__ int s[256];
  int t = threadIdx.x;
  int i = blockIdx.x * 256 + t;
  s[t] = (i < N) ? cnt[i] : 0;
  __syncthreads();
  for (int off = 128; off > 0; off >>= 1) {
    if (t < off) s[t] += s[t + off];
    __syncthreads();
  }
  if (t == 0) bsum[blockIdx.x] = s[0];
}

__global__ __launch_bounds__(512) void k_scan_bsum(const int* __restrict__ bsum,
                                                   int* __restrict__ bofs, int nb) {
  __shared__ int s[512];
  __shared__ int carry;
  int t = threadIdx.x;
  if (t == 0) carry = 0;
  __syncthreads();
  for (int base = 0; base < nb; base += 512) {
    int i = base + t;
    int v = (i < nb) ? bsum[i] : 0;
    s[t] = v;
    __syncthreads();
    for (int off = 1; off < 512; off <<= 1) {
      int a = (t >= off) ? s[t - off] : 0;
      __syncthreads();
      s[t] += a;
      __syncthreads();
    }
    if (i < nb) bofs[i] = carry + s[t] - v;
    __syncthreads();
    if (t == 0) carry += s[511];
    __syncthreads();
  }
}

__global__ __launch_bounds__(256) void k_scan_write(const int* __restrict__ cnt,
                                                    const int* __restrict__ bofs,
                                                    int* __restrict__ row_ptr, int N) {
  __shared__ int s[256];
  int t = threadIdx.x;
  int i = blockIdx.x * 256 + t;
  int v = (i < N) ? cnt[i] : 0;
  s[t] = v;
  __syncthreads();
  for (int off = 1; off < 256; off <<= 1) {
    int a = (t >= off) ? s[t - off] : 0;
    __syncthreads();
    s[t] += a;
    __syncthreads();
  }
  int excl = bofs[blockIdx.x] + s[t] - v;
  if (i < N) row_ptr[i] = excl;
  if (i == N - 1) row_ptr[N] = excl + v;
}

__global__ void k_fill(const int* __restrict__ row, const int* __restrict__ col, int E,
                       const float* __restrict__ dinv, const int* __restrict__ row_ptr,
                       int* __restrict__ fill, int* __restrict__ csr_src,
                       float* __restrict__ csr_nrm) {
  int e = blockIdx.x * blockDim.x + threadIdx.x;
  if (e >= E) return;
  int r = row[e], c = col[e];
  int p = row_ptr[c] + atomicAdd(&fill[c], 1);
  csr_src[p] = r;
  csr_nrm[p] = dinv[r] * dinv[c];
}

__global__ void k_f2h(const float* __restrict__ src, __half* __restrict__ dst, int n) {
  int base = (blockIdx.x * blockDim.x + threadIdx.x) * 4;
  if (base < n) {
    float4 v = *(const float4*)(src + base);
    __half2* d = (__half2*)(dst + base);
    d[0] = __floats2half2_rn(v.x, v.y);
    d[1] = __floats2half2_rn(v.z, v.w);
  }
}

// ---------------- aggregation (one wave per node, fp16 gather, atomic-free) ----------------

__global__ __launch_bounds__(256) void k_aggregate16(
    const __half* __restrict__ h, const float* __restrict__ x0,
    const float* __restrict__ dinv, const int* __restrict__ row_ptr,
    const int* __restrict__ csr_src, const float* __restrict__ csr_nrm,
    float* __restrict__ support, int N) {
  int node = blockIdx.x * 4 + (threadIdx.x >> 6);
  if (node >= N) return;
  int lane = threadIdx.x & 63;
  int beg = row_ptr[node], end = row_ptr[node + 1];
  float di = dinv[node];
  // self-loop term
  float2 f0 = __half22float2(((const __half2*)(h + (size_t)node * HID))[lane]);
  float ax = di * di * f0.x;
  float ay = di * di * f0.y;
  int j = beg;
  for (; j + 4 <= end; j += 4) {
    int s0 = csr_src[j], s1 = csr_src[j + 1], s2 = csr_src[j + 2], s3 = csr_src[j + 3];
    float w0 = csr_nrm[j], w1 = csr_nrm[j + 1], w2 = csr_nrm[j + 2], w3 = csr_nrm[j + 3];
    __half2 a0 = ((const __half2*)(h + (size_t)s0 * HID))[lane];
    __half2 a1 = ((const __half2*)(h + (size_t)s1 * HID))[lane];
    __half2 a2 = ((const __half2*)(h + (size_t)s2 * HID))[lane];
    __half2 a3 = ((const __half2*)(h + (size_t)s3 * HID))[lane];
    float2 f;
    f = __half22float2(a0); ax = fmaf(w0, f.x, ax); ay = fmaf(w0, f.y, ay);
    f = __half22float2(a1); ax = fmaf(w1, f.x, ax); ay = fmaf(w1, f.y, ay);
    f = __half22float2(a2); ax = fmaf(w2, f.x, ax); ay = fmaf(w2, f.y, ay);
    f = __half22float2(a3); ax = fmaf(w3, f.x, ax); ay = fmaf(w3, f.y, ay);
  }
  for (; j < end; ++j) {
    int s = csr_src[j];
    float w = csr_nrm[j];
    float2 f = __half22float2(((const __half2*)(h + (size_t)s * HID))[lane]);
    ax = fmaf(w, f.x, ax);
    ay = fmaf(w, f.y, ay);
  }
  float2 xv = ((const float2*)(x0 + (size_t)node * HID))[lane];
  float2 o;
  o.x = 0.9f * ax + 0.1f * xv.x;
  o.y = 0.9f * ay + 0.1f * xv.y;
  ((float2*)(support + (size_t)node * HID))[lane] = o;
}

// ---------------- fp32 tiled GEMM: C[M][NC] = op(A[M][128] @ B[128][NC]) ----------------
// AHALF: A is fp16.  OHALF: C written fp16.

template <int NC, bool RELU, bool BIAS, bool AHALF, bool OHALF>
__global__ __launch_bounds__(256) void k_gemm(const void* __restrict__ Av,
                                              const float* __restrict__ B,
                                              const float* __restrict__ bias,
                                              void* __restrict__ Cv, int M) {
  constexpr int TN = NC / 16;             // 8 (NC=128) or 4 (NC=64)
  __shared__ float As[8][68];             // transposed tile
  __shared__ float Bs[8][NC];
  int tid = threadIdx.x;
  int tx = tid & 15, ty = tid >> 4;
  int row0 = blockIdx.x * 64;

  float acc[4][TN];
#pragma unroll
  for (int m = 0; m < 4; ++m)
#pragma unroll
    for (int n = 0; n < TN; ++n) acc[m][n] = 0.0f;

  int la_row = tid >> 2;        // 0..63
  int la_k = (tid & 3) * 2;     // 0,2,4,6

  for (int kk = 0; kk < 128; kk += 8) {
    int ar = row0 + la_row;
    float2 av = make_float2(0.0f, 0.0f);
    if (ar < M) {
      if (AHALF) {
        const __half* Ah = (const __half*)Av;
        av = __half22float2(*(const __half2*)(Ah + (size_t)ar * 128 + kk + la_k));
      } else {
        av = *(const float2*)((const float*)Av + (size_t)ar * 128 + kk + la_k);
      }
    }
    As[la_k][la_row] = av.x;
    As[la_k + 1][la_row] = av.y;
    if (NC == 128) {
      int bk = tid >> 5, bc = (tid & 31) * 4;
      *(float4*)&Bs[bk][bc] = *(const float4*)(B + (size_t)(kk + bk) * NC + bc);
    } else {
      if (tid < NC * 2) {
        int bk = tid >> 4, bc = (tid & 15) * 4;
        *(float4*)&Bs[bk][bc] = *(const float4*)(B + (size_t)(kk + bk) * NC + bc);
      }
    }
    __syncthreads();
#pragma unroll
    for (int k = 0; k < 8; ++k) {
      float a[4], b[TN];
      *(float4*)a = *(const float4*)&As[k][ty * 4];
#pragma unroll
      for (int n = 0; n < TN; n += 4)
        *(float4*)&b[n] = *(const float4*)&Bs[k][tx * TN + n];
#pragma unroll
      for (int m = 0; m < 4; ++m)
#pragma unroll
        for (int n = 0; n < TN; ++n) acc[m][n] = fmaf(a[m], b[n], acc[m][n]);
    }
    __syncthreads();
  }

#pragma unroll
  for (int m = 0; m < 4; ++m) {
    int r = row0 + ty * 4 + m;
    if (r >= M) continue;
    float v[TN];
#pragma unroll
    for (int n = 0; n < TN; ++n) {
      v[n] = acc[m][n];
      if (BIAS) v[n] += bias[tx * TN + n];
      if (RELU) v[n] = fmaxf(v[n], 0.0f);
    }
    if (OHALF) {
      __half* Ch = (__half*)Cv;
      __half2 hp[TN / 2];
#pragma unroll
      for (int n = 0; n < TN; n += 2) hp[n / 2] = __floats2half2_rn(v[n], v[n + 1]);
      if (TN == 8)
        *(float4*)(Ch + (size_t)r * NC + tx * TN) = *(float4*)hp;
      else
        *(float2*)(Ch + (size_t)r * NC + tx * TN) = *(float2*)hp;
    } else {
      float* Cf = (float*)Cv;
#pragma unroll
      for (int n = 0; n < TN; n += 4) {
        float4 o;
        o.x = v[n + 0]; o.y = v[n + 1]; o.z = v[n + 2]; o.w = v[n + 3];
        *(float4*)(Cf + (size_t)r * NC + tx * TN + n) = o;
      }
    }
  }
}

// ---------------- launch ----------------

extern "C" void kernel_launch(void* const* d_in, const int* in_sizes, int n_in,
                              void* d_out, int out_size, void* d_ws, size_t ws_size,
                              hipStream_t stream) {
  const float* x     = (const float*)d_in[0];
  const int*   ei    = (const int*)d_in[1];
  const float* W_in  = (const float*)d_in[2];
  const float* b_in  = (const float*)d_in[3];
  const float* Wc    = (const float*)d_in[4];
  const float* W_out = (const float*)d_in[5];
  const float* b_out = (const float*)d_in[6];
  float* out = (float*)d_out;

  const int N = in_sizes[0] / HID;          // 100000
  const int E = in_sizes[1] / 2;            // 1600000
  const int L = in_sizes[4] / (HID * HID);  // 8
  const int nb = (N + 255) / 256;           // scan blocks
  const int* row = ei;       // sources
  const int* col = ei + E;   // targets

  char* p = (char*)d_ws;
  auto alloc = [&](size_t bytes) {
    char* q = p;
    p += (bytes + 255) & ~(size_t)255;
    return q;
  };
  int*    cnt     = (int*)alloc((size_t)N * 4);
  int*    row_ptr = (int*)alloc((size_t)(N + 1) * 4);
  int*    fill    = (int*)alloc((size_t)N * 4);
  int*    bsum    = (int*)alloc((size_t)nb * 4);
  int*    bofs    = (int*)alloc((size_t)nb * 4);
  float*  dinv    = (float*)alloc((size_t)N * 4);
  int*    csr_src = (int*)alloc((size_t)E * 4);
  float*  csr_nrm = (float*)alloc((size_t)E * 4);
  float*  x0      = (float*)alloc((size_t)N * HID * 4);
  float*  sup     = (float*)alloc((size_t)N * HID * 4);
  __half* x0h     = (__half*)alloc((size_t)N * HID * 2);
  __half* h16     = (__half*)alloc((size_t)N * HID * 2);
  (void)ws_size; (void)n_in; (void)out_size;

  hipMemsetAsync(cnt, 0, (size_t)N * 4, stream);
  hipMemsetAsync(fill, 0, (size_t)N * 4, stream);

  k_hist<<<(E + 255) / 256, 256, 0, stream>>>(col, E, cnt);
  k_dinv<<<(N + 255) / 256, 256, 0, stream>>>(cnt, dinv, N);
  k_blocksum<<<nb, 256, 0, stream>>>(cnt, bsum, N);
  k_scan_bsum<<<1, 512, 0, stream>>>(bsum, bofs, nb);
  k_scan_write<<<nb, 256, 0, stream>>>(cnt, bofs, row_ptr, N);
  k_fill<<<(E + 255) / 256, 256, 0, stream>>>(row, col, E, dinv, row_ptr, fill,
                                              csr_src, csr_nrm);

  int ggrid = (N + 63) / 64;
  // input projection -> x0 (fp32) and x0h (fp16 copy for gather)
  k_gemm<128, true, true, false, false><<<ggrid, 256, 0, stream>>>(x, W_in, b_in, x0, N);
  k_f2h<<<(N * HID / 4 + 255) / 256, 256, 0, stream>>>(x0, x0h, N * HID);

  const __half* hin = x0h;
  for (int l = 0; l < L; ++l) {
    k_aggregate16<<<(N + 3) / 4, 256, 0, stream>>>(hin, x0, dinv, row_ptr, csr_src,
                                                   csr_nrm, sup, N);
    k_gemm<128, true, false, false, true><<<ggrid, 256, 0, stream>>>(
        sup, Wc + (size_t)l * HID * HID, nullptr, h16, N);
    hin = h16;
  }
  // output projection (A is fp16 h)
  k_gemm<64, false, true, true, false><<<ggrid, 256, 0, stream>>>(h16, W_out, b_out, out, N);
}

// Round 3
// 1240.181 us; speedup vs baseline: 1.7547x; 1.0588x over previous
//
#include <hip/hip_runtime.h>
#include <hip/hip_fp16.h>
#include <cstdint>
#include <cstddef>

// GCNII: h0 = relu(x@W_in + b_in); 8x { agg = Ahat @ h; s = .9 agg + .1 h0; h = relu(s @ Wl) };
// out = h@W_out + b_out.  Ahat = D^-1/2 (A + I) D^-1/2 (deg over targets, +1 self loop).
// Activations (x0, support, h) stored fp16; GEMM accumulation fp32; weights fp32.
// CSR packed int2{src, norm_bits} -> single 8B scatter per edge in k_fill.

#define HID 128

// ---------------- preprocessing ----------------

__global__ void k_hist(const int* __restrict__ col, int E, int* __restrict__ cnt) {
  int e = blockIdx.x * blockDim.x + threadIdx.x;
  if (e < E) atomicAdd(&cnt[col[e]], 1);
}

__global__ void k_dinv(const int* __restrict__ cnt, float* __restrict__ dinv, int N) {
  int i = blockIdx.x * blockDim.x + threadIdx.x;
  if (i < N) dinv[i] = rsqrtf((float)cnt[i] + 1.0f);  // +1 self loop
}

// hierarchical exclusive scan
__global__ __launch_bounds__(256) void k_blocksum(const int* __restrict__ cnt,
                                                  int* __restrict__ bsum, int N) {
  __shared__ int s[256];
  int t = threadIdx.x;
  int i = blockIdx.x * 256 + t;
  s[t] = (i < N) ? cnt[i] : 0;
  __syncthreads();
  for (int off = 128; off > 0; off >>= 1) {
    if (t < off) s[t] += s[t + off];
    __syncthreads();
  }
  if (t == 0) bsum[blockIdx.x] = s[0];
}

__global__ __launch_bounds__(512) void k_scan_bsum(const int* __restrict__ bsum,
                                                   int* __restrict__ bofs, int nb) {
  __shared__ int s[512];
  __shared__ int carry;
  int t = threadIdx.x;
  if (t == 0) carry = 0;
  __syncthreads();
  for (int base = 0; base < nb; base += 512) {
    int i = base + t;
    int v = (i < nb) ? bsum[i] : 0;
    s[t] = v;
    __syncthreads();
    for (int off = 1; off < 512; off <<= 1) {
      int a = (t >= off) ? s[t - off] : 0;
      __syncthreads();
      s[t] += a;
      __syncthreads();
    }
    if (i < nb) bofs[i] = carry + s[t] - v;
    __syncthreads();
    if (t == 0) carry += s[511];
    __syncthreads();
  }
}

__global__ __launch_bounds__(256) void k_scan_write(const int* __restrict__ cnt,
                                                    const int* __restrict__ bofs,
                                                    int* __restrict__ row_ptr, int N) {
  __shared__ int s[256];
  int t = threadIdx.x;
  int i = blockIdx.x * 256 + t;
  int v = (i < N) ? cnt[i] : 0;
  s[t] = v;
  __syncthreads();
  for (int off = 1; off < 256; off <<= 1) {
    int a = (t >= off) ? s[t - off] : 0;
    __syncthreads();
    s[t] += a;
    __syncthreads();
  }
  int excl = bofs[blockIdx.x] + s[t] - v;
  if (i < N) row_ptr[i] = excl;
  if (i == N - 1) row_ptr[N] = excl + v;
}

__global__ void k_fill(const int* __restrict__ row, const int* __restrict__ col, int E,
                       const float* __restrict__ dinv, const int* __restrict__ row_ptr,
                       int* __restrict__ fill, int2* __restrict__ csr) {
  int e = blockIdx.x * blockDim.x + threadIdx.x;
  if (e >= E) return;
  int r = row[e], c = col[e];
  int p = row_ptr[c] + atomicAdd(&fill[c], 1);
  csr[p] = make_int2(r, __float_as_int(dinv[r] * dinv[c]));
}

// ---------------- aggregation (one wave per node, fp16 gather, atomic-free) ----------------

__global__ __launch_bounds__(256) void k_aggregate16(
    const __half* __restrict__ h, const __half* __restrict__ x0h,
    const float* __restrict__ dinv, const int* __restrict__ row_ptr,
    const int2* __restrict__ csr, __half* __restrict__ support, int N) {
  int node = blockIdx.x * 4 + (threadIdx.x >> 6);
  if (node >= N) return;
  int lane = threadIdx.x & 63;
  int beg = row_ptr[node], end = row_ptr[node + 1];
  float di = dinv[node];
  // self-loop term
  float2 f0 = __half22float2(((const __half2*)(h + (size_t)node * HID))[lane]);
  float ax = di * di * f0.x;
  float ay = di * di * f0.y;
  int j = beg;
  for (; j + 4 <= end; j += 4) {
    int2 e0 = csr[j], e1 = csr[j + 1], e2 = csr[j + 2], e3 = csr[j + 3];
    __half2 a0 = ((const __half2*)(h + (size_t)e0.x * HID))[lane];
    __half2 a1 = ((const __half2*)(h + (size_t)e1.x * HID))[lane];
    __half2 a2 = ((const __half2*)(h + (size_t)e2.x * HID))[lane];
    __half2 a3 = ((const __half2*)(h + (size_t)e3.x * HID))[lane];
    float w0 = __int_as_float(e0.y), w1 = __int_as_float(e1.y);
    float w2 = __int_as_float(e2.y), w3 = __int_as_float(e3.y);
    float2 f;
    f = __half22float2(a0); ax = fmaf(w0, f.x, ax); ay = fmaf(w0, f.y, ay);
    f = __half22float2(a1); ax = fmaf(w1, f.x, ax); ay = fmaf(w1, f.y, ay);
    f = __half22float2(a2); ax = fmaf(w2, f.x, ax); ay = fmaf(w2, f.y, ay);
    f = __half22float2(a3); ax = fmaf(w3, f.x, ax); ay = fmaf(w3, f.y, ay);
  }
  for (; j < end; ++j) {
    int2 e = csr[j];
    float w = __int_as_float(e.y);
    float2 f = __half22float2(((const __half2*)(h + (size_t)e.x * HID))[lane]);
    ax = fmaf(w, f.x, ax);
    ay = fmaf(w, f.y, ay);
  }
  float2 xv = __half22float2(((const __half2*)(x0h + (size_t)node * HID))[lane]);
  float ox = 0.9f * ax + 0.1f * xv.x;
  float oy = 0.9f * ay + 0.1f * xv.y;
  ((__half2*)(support + (size_t)node * HID))[lane] = __floats2half2_rn(ox, oy);
}

// ---------------- GEMM: C[M][NC] = op(A[M][128] @ B[128][NC]) ----------------
// 128x128 block tile (128xNC for NC=64), 256 threads, 8x(NC/16) micro-tile, BK=16.
// AHALF: A fp16.  OHALF: C written fp16.  fp32 accumulation.

template <int NC, bool RELU, bool BIAS, bool AHALF, bool OHALF>
__global__ __launch_bounds__(256) void k_gemm(const void* __restrict__ Av,
                                              const float* __restrict__ B,
                                              const float* __restrict__ bias,
                                              void* __restrict__ Cv, int M) {
  constexpr int TN = NC / 16;  // 8 (NC=128) or 4 (NC=64)
  __shared__ float As[16][128];
  __shared__ float Bs[16][NC];
  int tid = threadIdx.x;
  int tx = tid & 15, ty = tid >> 4;
  int row0 = blockIdx.x * 128;

  float acc[8][TN];
#pragma unroll
  for (int m = 0; m < 8; ++m)
#pragma unroll
    for (int n = 0; n < TN; ++n) acc[m][n] = 0.0f;

  int la_row = tid >> 1;        // 0..127
  int la_k = (tid & 1) * 8;     // 0 or 8
  int ar = row0 + la_row;
  int bk = tid >> 4;            // 0..15
  int bc = (tid & 15) * 4;      // 0..60

  for (int kk = 0; kk < 128; kk += 16) {
    // stage A (transposed into As[k][row])
    float f[8];
    if (ar < M) {
      if (AHALF) {
        const __half* Ah = (const __half*)Av;
        float4 raw = *(const float4*)(Ah + (size_t)ar * 128 + kk + la_k);
        const __half2* hp = (const __half2*)&raw;
#pragma unroll
        for (int i = 0; i < 4; ++i) {
          float2 t2 = __half22float2(hp[i]);
          f[2 * i] = t2.x;
          f[2 * i + 1] = t2.y;
        }
      } else {
        const float* Af = (const float*)Av;
        *(float4*)&f[0] = *(const float4*)(Af + (size_t)ar * 128 + kk + la_k);
        *(float4*)&f[4] = *(const float4*)(Af + (size_t)ar * 128 + kk + la_k + 4);
      }
    } else {
#pragma unroll
      for (int i = 0; i < 8; ++i) f[i] = 0.0f;
    }
#pragma unroll
    for (int i = 0; i < 8; ++i) As[la_k + i][la_row] = f[i];
    // stage B
    *(float4*)&Bs[bk][bc] = *(const float4*)(B + (size_t)(kk + bk) * NC + bc);
    if (TN == 8)
      *(float4*)&Bs[bk][64 + bc] = *(const float4*)(B + (size_t)(kk + bk) * NC + 64 + bc);
    __syncthreads();
#pragma unroll
    for (int k = 0; k < 16; ++k) {
      float a[8], b[TN];
      *(float4*)&a[0] = *(const float4*)&As[k][ty * 8];
      *(float4*)&a[4] = *(const float4*)&As[k][ty * 8 + 4];
      *(float4*)&b[0] = *(const float4*)&Bs[k][tx * 4];
      if (TN == 8) *(float4*)&b[4] = *(const float4*)&Bs[k][64 + tx * 4];
#pragma unroll
      for (int m = 0; m < 8; ++m)
#pragma unroll
        for (int n = 0; n < TN; ++n) acc[m][n] = fmaf(a[m], b[n], acc[m][n]);
    }
    __syncthreads();
  }

#pragma unroll
  for (int m = 0; m < 8; ++m) {
    int r = row0 + ty * 8 + m;
    if (r >= M) continue;
    float v[TN];
#pragma unroll
    for (int n = 0; n < TN; ++n) {
      int c = (n < 4) ? (tx * 4 + n) : (64 + tx * 4 + n - 4);
      v[n] = acc[m][n];
      if (BIAS) v[n] += bias[c];
      if (RELU) v[n] = fmaxf(v[n], 0.0f);
    }
    if (OHALF) {
      __half* Ch = (__half*)Cv;
      __half2 h01 = __floats2half2_rn(v[0], v[1]);
      __half2 h23 = __floats2half2_rn(v[2], v[3]);
      float2 pk0;
      ((__half2*)&pk0)[0] = h01;
      ((__half2*)&pk0)[1] = h23;
      *(float2*)(Ch + (size_t)r * NC + tx * 4) = pk0;
      if (TN == 8) {
        __half2 h45 = __floats2half2_rn(v[4], v[5]);
        __half2 h67 = __floats2half2_rn(v[6], v[7]);
        float2 pk1;
        ((__half2*)&pk1)[0] = h45;
        ((__half2*)&pk1)[1] = h67;
        *(float2*)(Ch + (size_t)r * NC + 64 + tx * 4) = pk1;
      }
    } else {
      float* Cf = (float*)Cv;
      *(float4*)(Cf + (size_t)r * NC + tx * 4) = *(float4*)&v[0];
      if (TN == 8) *(float4*)(Cf + (size_t)r * NC + 64 + tx * 4) = *(float4*)&v[4];
    }
  }
}

// ---------------- launch ----------------

extern "C" void kernel_launch(void* const* d_in, const int* in_sizes, int n_in,
                              void* d_out, int out_size, void* d_ws, size_t ws_size,
                              hipStream_t stream) {
  const float* x     = (const float*)d_in[0];
  const int*   ei    = (const int*)d_in[1];
  const float* W_in  = (const float*)d_in[2];
  const float* b_in  = (const float*)d_in[3];
  const float* Wc    = (const float*)d_in[4];
  const float* W_out = (const float*)d_in[5];
  const float* b_out = (const float*)d_in[6];
  float* out = (float*)d_out;

  const int N = in_sizes[0] / HID;          // 100000
  const int E = in_sizes[1] / 2;            // 1600000
  const int L = in_sizes[4] / (HID * HID);  // 8
  const int nb = (N + 255) / 256;           // scan blocks
  const int* row = ei;       // sources
  const int* col = ei + E;   // targets

  char* p = (char*)d_ws;
  auto alloc = [&](size_t bytes) {
    char* q = p;
    p += (bytes + 255) & ~(size_t)255;
    return q;
  };
  int*    cnt     = (int*)alloc((size_t)N * 4);
  int*    row_ptr = (int*)alloc((size_t)(N + 1) * 4);
  int*    fill    = (int*)alloc((size_t)N * 4);
  int*    bsum    = (int*)alloc((size_t)nb * 4);
  int*    bofs    = (int*)alloc((size_t)nb * 4);
  float*  dinv    = (float*)alloc((size_t)N * 4);
  int2*   csr     = (int2*)alloc((size_t)E * 8);
  __half* x0h     = (__half*)alloc((size_t)N * HID * 2);
  __half* sup16   = (__half*)alloc((size_t)N * HID * 2);
  __half* h16     = (__half*)alloc((size_t)N * HID * 2);
  (void)ws_size; (void)n_in; (void)out_size;

  hipMemsetAsync(cnt, 0, (size_t)N * 4, stream);
  hipMemsetAsync(fill, 0, (size_t)N * 4, stream);

  k_hist<<<(E + 255) / 256, 256, 0, stream>>>(col, E, cnt);
  k_dinv<<<(N + 255) / 256, 256, 0, stream>>>(cnt, dinv, N);
  k_blocksum<<<nb, 256, 0, stream>>>(cnt, bsum, N);
  k_scan_bsum<<<1, 512, 0, stream>>>(bsum, bofs, nb);
  k_scan_write<<<nb, 256, 0, stream>>>(cnt, bofs, row_ptr, N);
  k_fill<<<(E + 255) / 256, 256, 0, stream>>>(row, col, E, dinv, row_ptr, fill, csr);

  int ggrid = (N + 127) / 128;
  // input projection -> x0h (fp16)
  k_gemm<128, true, true, false, true><<<ggrid, 256, 0, stream>>>(x, W_in, b_in, x0h, N);

  const __half* hin = x0h;
  for (int l = 0; l < L; ++l) {
    k_aggregate16<<<(N + 3) / 4, 256, 0, stream>>>(hin, x0h, dinv, row_ptr, csr,
                                                   sup16, N);
    k_gemm<128, true, false, true, true><<<ggrid, 256, 0, stream>>>(
        sup16, Wc + (size_t)l * HID * HID, nullptr, h16, N);
    hin = h16;
  }
  // output projection (A fp16, out fp32)
  k_gemm<64, false, true, true, false><<<ggrid, 256, 0, stream>>>(h16, W_out, b_out,
                                                                  out, N);
}